// Round 3
// baseline (670.730 us; speedup 1.0000x reference)
//
#include <hip/hip_runtime.h>
#include <hip/hip_bf16.h>

#define S_ 4096
#define D_ 256
#define B_ 4
#define NCT 32  // number of 128-wide col tiles per row in k_qk

static constexpr float INV_SCALE = 0.08838834764831844f; // 1/sqrt(128)

typedef __bf16 bf16x8 __attribute__((ext_vector_type(8)));
typedef float f32x4 __attribute__((ext_vector_type(4)));

// XOR swizzle for [row][64 bf16] tiles (128B rows)
__device__ __forceinline__ int swz(int row, int kbyte) {
    return (row * 128 + kbyte) ^ ((row & 7) << 4);
}
// XOR swizzle for [row][128 bf16] tiles (256B rows)
__device__ __forceinline__ int swz256(int row, int kbyte) {
    return (row * 256 + kbyte) ^ ((row & 7) << 4);
}

__device__ __forceinline__ uint2 pack4(float4 f) {
    union { __bf16 h[4]; uint2 u; } r;
    r.h[0] = (__bf16)f.x; r.h[1] = (__bf16)f.y;
    r.h[2] = (__bf16)f.z; r.h[3] = (__bf16)f.w;
    return r.u;
}

// ---------------------------------------------------------------------------
// K1: raw scores = Q . K^T  (+ optional per-row tile softmax stats to ws)
// tile 128x128, BK=64, 4 waves 2x2, wave = 64x64 (4x4 fragments)
// ---------------------------------------------------------------------------
template <bool STATS>
__global__ __launch_bounds__(256, 4) void k_qk(const float* __restrict__ Q,
                                               const float* __restrict__ Km,
                                               float* __restrict__ Wt,
                                               float2* __restrict__ stats) {
    __shared__ alignas(16) unsigned short Qs[128 * 64];
    __shared__ alignas(16) unsigned short Ks[128 * 64];
    __shared__ float s_mx[4][64];
    __shared__ float s_sm[4][64];
    const int t = threadIdx.x;
    const int lane = t & 63;
    const int wv = t >> 6;
    const int wm = wv >> 1, wn = wv & 1;
    const int mb = blockIdx.x * 128, nb = blockIdx.y * 128;
    const int b = blockIdx.z;
    const float* Qb = Q + (size_t)b * S_ * D_;
    const float* Kb = Km + (size_t)b * S_ * D_;

    f32x4 acc[4][4];
#pragma unroll
    for (int i = 0; i < 4; i++)
#pragma unroll
        for (int j = 0; j < 4; j++) acc[i][j] = f32x4{0.f, 0.f, 0.f, 0.f};

    const int srow = t >> 4;        // 0..15
    const int scol = (t & 15) * 4;  // float col within 64-wide k slab

    for (int kb = 0; kb < D_; kb += 64) {
        __syncthreads();  // previous iter's fragment reads done
#pragma unroll
        for (int h = 0; h < 2; h++) {
            float4 fq[4], fk[4];
#pragma unroll
            for (int p = 0; p < 4; p++) {
                int r = srow + (h * 4 + p) * 16;
                fq[p] = *reinterpret_cast<const float4*>(Qb + (size_t)(mb + r) * D_ + kb + scol);
                fk[p] = *reinterpret_cast<const float4*>(Kb + (size_t)(nb + r) * D_ + kb + scol);
            }
#pragma unroll
            for (int p = 0; p < 4; p++) {
                int r = srow + (h * 4 + p) * 16;
                *reinterpret_cast<uint2*>((char*)Qs + swz(r, scol * 2)) = pack4(fq[p]);
                *reinterpret_cast<uint2*>((char*)Ks + swz(r, scol * 2)) = pack4(fk[p]);
            }
        }
        __syncthreads();
#pragma unroll
        for (int ks = 0; ks < 2; ks++) {
            const int kby = ks * 64 + (lane >> 4) * 16;
            bf16x8 a[4], bb[4];
#pragma unroll
            for (int m = 0; m < 4; m++) {
                int r = wm * 64 + m * 16 + (lane & 15);
                a[m] = *reinterpret_cast<const bf16x8*>((const char*)Qs + swz(r, kby));
            }
#pragma unroll
            for (int n = 0; n < 4; n++) {
                int r = wn * 64 + n * 16 + (lane & 15);
                bb[n] = *reinterpret_cast<const bf16x8*>((const char*)Ks + swz(r, kby));
            }
#pragma unroll
            for (int m = 0; m < 4; m++)
#pragma unroll
                for (int n = 0; n < 4; n++)
                    acc[m][n] = __builtin_amdgcn_mfma_f32_16x16x32_bf16(a[m], bb[n], acc[m][n], 0, 0, 0);
        }
    }

    // write raw scores
    float* Wb = Wt + (size_t)b * S_ * S_;
#pragma unroll
    for (int m = 0; m < 4; m++) {
#pragma unroll
        for (int j = 0; j < 4; j++) {
            int row = mb + wm * 64 + m * 16 + (lane >> 4) * 4 + j;
            float* rp = Wb + (size_t)row * S_ + nb + wn * 64 + (lane & 15);
#pragma unroll
            for (int n = 0; n < 4; n++) rp[n * 16] = acc[m][n][j];
        }
    }

    if (STATS) {
        const int grp = lane >> 4;
#pragma unroll
        for (int m = 0; m < 4; m++) {
#pragma unroll
            for (int j = 0; j < 4; j++) {
                float s0 = acc[m][0][j] * INV_SCALE;
                float s1 = acc[m][1][j] * INV_SCALE;
                float s2 = acc[m][2][j] * INV_SCALE;
                float s3 = acc[m][3][j] * INV_SCALE;
                float mx = fmaxf(fmaxf(s0, s1), fmaxf(s2, s3));
#pragma unroll
                for (int o = 8; o; o >>= 1) mx = fmaxf(mx, __shfl_xor(mx, o, 64));
                float se = __expf(s0 - mx) + __expf(s1 - mx) + __expf(s2 - mx) + __expf(s3 - mx);
#pragma unroll
                for (int o = 8; o; o >>= 1) se += __shfl_xor(se, o, 64);
                if ((lane & 15) == 0) {
                    int rw = m * 16 + grp * 4 + j;
                    s_mx[wv][rw] = mx;
                    s_sm[wv][rw] = se;
                }
            }
        }
        __syncthreads();
        if (t < 128) {
            int wm2 = t >> 6, rw = t & 63;
            float m0 = s_mx[wm2 * 2][rw], m1 = s_mx[wm2 * 2 + 1][rw];
            float mm = fmaxf(m0, m1);
            float ll = s_sm[wm2 * 2][rw] * __expf(m0 - mm) + s_sm[wm2 * 2 + 1][rw] * __expf(m1 - mm);
            int row = mb + wm2 * 64 + rw;
            stats[((size_t)b * S_ + row) * NCT + blockIdx.y] = make_float2(mm, ll);
        }
    }
}

// ---------------------------------------------------------------------------
// K2: combine 32 per-tile (max,sumexp) partials -> (m, 1/l) per row
// ---------------------------------------------------------------------------
__global__ __launch_bounds__(256) void k_reduce(const float2* __restrict__ stats,
                                                float2* __restrict__ finals) {
    const int r = blockIdx.x * 256 + threadIdx.x;  // 0..B*S-1
    const float2* p = stats + (size_t)r * NCT;
    float2 v[NCT];
    float m = -1e30f;
#pragma unroll
    for (int i = 0; i < NCT; i++) { v[i] = p[i]; m = fmaxf(m, v[i].x); }
    float l = 0.f;
#pragma unroll
    for (int i = 0; i < NCT; i++) l += v[i].y * __expf(v[i].x - m);
    finals[r] = make_float2(m, 1.0f / l);
}

// ---------------------------------------------------------------------------
// k_vt: V [b][4096][256] fp32 -> Vt [b][256][4096] bf16 (workspace)
// ---------------------------------------------------------------------------
__global__ __launch_bounds__(256) void k_vt(const float* __restrict__ V,
                                            unsigned short* __restrict__ Vt) {
    __shared__ float tile[64][65];
    const int t = threadIdx.x;
    const int kb = blockIdx.x * 64;  // S dim
    const int nb = blockIdx.y * 64;  // D dim
    const int b = blockIdx.z;
    const float* Vb = V + (size_t)b * S_ * D_;
    {
        const int r = t >> 2, c4 = (t & 3) * 16;
#pragma unroll
        for (int j = 0; j < 4; j++) {
            float4 f = *reinterpret_cast<const float4*>(Vb + (size_t)(kb + r) * D_ + nb + c4 + j * 4);
            tile[r][c4 + j * 4 + 0] = f.x;
            tile[r][c4 + j * 4 + 1] = f.y;
            tile[r][c4 + j * 4 + 2] = f.z;
            tile[r][c4 + j * 4 + 3] = f.w;
        }
    }
    __syncthreads();
    {
        const int n = t >> 2, k4 = (t & 3) * 16;
        union { __bf16 h[16]; uint4 u[2]; } o;
#pragma unroll
        for (int j = 0; j < 16; j++) o.h[j] = (__bf16)tile[k4 + j][n];
        unsigned short* Ob = Vt + (size_t)b * D_ * S_ + (size_t)(nb + n) * S_ + kb + k4;
        *reinterpret_cast<uint4*>(Ob) = o.u[0];
        *reinterpret_cast<uint4*>(Ob + 8) = o.u[1];
    }
}

// ---------------------------------------------------------------------------
// K3 (fused): read raw scores, normalize (exp(s*scale-m)*invl), write W
// in-place, and accumulate Out = W . V via MFMA with V^T in swizzled LDS.
// Mtile=32, N=256 full, BK=128, 256 thr (4 waves, wave = 32x64 out).
// ---------------------------------------------------------------------------
__global__ __launch_bounds__(256, 2) void k_pvn(float* __restrict__ Wt,
                                                const unsigned short* __restrict__ Vtg,
                                                const float2* __restrict__ finals,
                                                float* __restrict__ Out) {
    __shared__ alignas(16) unsigned short Ws[32 * 128];
    __shared__ alignas(16) unsigned short Vs[256 * 128];
    const int t = threadIdx.x, lane = t & 63, wv = t >> 6;
    const int mb = blockIdx.x * 32;
    const int b = blockIdx.y;
    float* Wb = Wt + (size_t)b * S_ * S_;
    const char* Vtb = (const char*)(Vtg + (size_t)b * D_ * S_);

    const int rrow = t >> 3;        // 0..31
    const int cb = (t & 7) * 16;    // float col base (16 floats per thread)
    const float2 st = finals[(size_t)b * S_ + mb + rrow];
    const float mrow = st.x, invl = st.y;

    f32x4 acc[2][4];
#pragma unroll
    for (int i = 0; i < 2; i++)
#pragma unroll
        for (int j = 0; j < 4; j++) acc[i][j] = f32x4{0.f, 0.f, 0.f, 0.f};

    for (int kb = 0; kb < S_; kb += 128) {
        // A) issue V^T tile loads (L2-resident) into regs
        uint4 vreg[16];
#pragma unroll
        for (int p = 0; p < 16; p++) {
            int L = p * 4096 + t * 16;
            int row = L >> 8, c = L & 255;
            vreg[p] = *reinterpret_cast<const uint4*>(Vtb + (size_t)row * (S_ * 2) + (size_t)kb * 2 + c);
        }
        // B) raw scores -> normalized weights (write in place) + pack to LDS
        {
            float* rp = Wb + (size_t)(mb + rrow) * S_ + kb + cb;
            float4 f[4];
#pragma unroll
            for (int j = 0; j < 4; j++) f[j] = *reinterpret_cast<const float4*>(rp + j * 4);
#pragma unroll
            for (int j = 0; j < 4; j++) {
                f[j].x = __expf(f[j].x * INV_SCALE - mrow) * invl;
                f[j].y = __expf(f[j].y * INV_SCALE - mrow) * invl;
                f[j].z = __expf(f[j].z * INV_SCALE - mrow) * invl;
                f[j].w = __expf(f[j].w * INV_SCALE - mrow) * invl;
            }
#pragma unroll
            for (int j = 0; j < 4; j++) *reinterpret_cast<float4*>(rp + j * 4) = f[j];
            union { __bf16 h[8]; uint4 u; } pk0, pk1;
#pragma unroll
            for (int j = 0; j < 2; j++) {
                const float* s = &f[j].x;
#pragma unroll
                for (int e = 0; e < 4; e++) pk0.h[j * 4 + e] = (__bf16)s[e];
            }
#pragma unroll
            for (int j = 0; j < 2; j++) {
                const float* s = &f[2 + j].x;
#pragma unroll
                for (int e = 0; e < 4; e++) pk1.h[j * 4 + e] = (__bf16)s[e];
            }
            *reinterpret_cast<uint4*>((char*)Ws + swz256(rrow, cb * 2)) = pk0.u;
            *reinterpret_cast<uint4*>((char*)Ws + swz256(rrow, cb * 2 + 16)) = pk1.u;
        }
        // C) V regs -> swizzled LDS
#pragma unroll
        for (int p = 0; p < 16; p++) {
            int L = p * 4096 + t * 16;
            int row = L >> 8;
            *reinterpret_cast<uint4*>((char*)Vs + (L ^ ((row & 7) << 4))) = vreg[p];
        }
        __syncthreads();
        // D) MFMA
#pragma unroll
        for (int ks = 0; ks < 4; ks++) {
            const int kby = ks * 64 + (lane >> 4) * 16;
            bf16x8 a[2], bv[4];
#pragma unroll
            for (int m = 0; m < 2; m++)
                a[m] = *reinterpret_cast<const bf16x8*>((const char*)Ws + swz256(m * 16 + (lane & 15), kby));
#pragma unroll
            for (int n = 0; n < 4; n++)
                bv[n] = *reinterpret_cast<const bf16x8*>((const char*)Vs + swz256(wv * 64 + n * 16 + (lane & 15), kby));
#pragma unroll
            for (int m = 0; m < 2; m++)
#pragma unroll
                for (int n = 0; n < 4; n++)
                    acc[m][n] = __builtin_amdgcn_mfma_f32_16x16x32_bf16(a[m], bv[n], acc[m][n], 0, 0, 0);
        }
        __syncthreads();
    }

    float* Ob = Out + (size_t)b * S_ * D_;
#pragma unroll
    for (int m = 0; m < 2; m++) {
#pragma unroll
        for (int j = 0; j < 4; j++) {
            int row = mb + m * 16 + (lane >> 4) * 4 + j;
            float* rp = Ob + (size_t)row * D_ + wv * 64 + (lane & 15);
#pragma unroll
            for (int n = 0; n < 4; n++) rp[n * 16] = acc[m][n][j];
        }
    }
}

// ---------------------------------------------------------------------------
// Fallback path kernels (round-2 structure, known-good)
// ---------------------------------------------------------------------------
__global__ __launch_bounds__(256) void k_softmax(float* __restrict__ Wt) {
    const size_t row = blockIdx.x;
    float* p = Wt + row * S_;
    const int t = threadIdx.x;
    const int lane = t & 63, wv = t >> 6;
    __shared__ float red[4];

    float4 x[4];
#pragma unroll
    for (int j = 0; j < 4; j++)
        x[j] = *reinterpret_cast<const float4*>(p + t * 4 + j * 1024);

    float mx = -1e30f;
#pragma unroll
    for (int j = 0; j < 4; j++) {
        x[j].x *= INV_SCALE; x[j].y *= INV_SCALE;
        x[j].z *= INV_SCALE; x[j].w *= INV_SCALE;
        mx = fmaxf(mx, fmaxf(fmaxf(x[j].x, x[j].y), fmaxf(x[j].z, x[j].w)));
    }
#pragma unroll
    for (int o = 32; o; o >>= 1) mx = fmaxf(mx, __shfl_xor(mx, o, 64));
    if (lane == 0) red[wv] = mx;
    __syncthreads();
    mx = fmaxf(fmaxf(red[0], red[1]), fmaxf(red[2], red[3]));
    __syncthreads();

    float sum = 0.f;
#pragma unroll
    for (int j = 0; j < 4; j++) {
        x[j].x = __expf(x[j].x - mx); x[j].y = __expf(x[j].y - mx);
        x[j].z = __expf(x[j].z - mx); x[j].w = __expf(x[j].w - mx);
        sum += x[j].x + x[j].y + x[j].z + x[j].w;
    }
#pragma unroll
    for (int o = 32; o; o >>= 1) sum += __shfl_xor(sum, o, 64);
    if (lane == 0) red[wv] = sum;
    __syncthreads();
    sum = red[0] + red[1] + red[2] + red[3];
    const float r = 1.0f / sum;
#pragma unroll
    for (int j = 0; j < 4; j++) {
        x[j].x *= r; x[j].y *= r; x[j].z *= r; x[j].w *= r;
        *reinterpret_cast<float4*>(p + t * 4 + j * 1024) = x[j];
    }
}

__global__ __launch_bounds__(256) void k_pv_fb(const float* __restrict__ Wt,
                                               const float* __restrict__ V,
                                               float* __restrict__ Out) {
    __shared__ alignas(16) unsigned short Ws[64 * 64];
    __shared__ alignas(16) unsigned short Vs[256 * 64];
    const int t = threadIdx.x, lane = t & 63, wv = t >> 6;
    const int mb = blockIdx.x * 64;
    const int b = blockIdx.y;
    const float* Wb = Wt + (size_t)b * S_ * S_;

    f32x4 acc[4][4];
#pragma unroll
    for (int i = 0; i < 4; i++)
#pragma unroll
        for (int j = 0; j < 4; j++) acc[i][j] = f32x4{0.f, 0.f, 0.f, 0.f};

    const int srow = t >> 4;
    const int scol = (t & 15) * 4;

    for (int kb = 0; kb < S_; kb += 64) {
        __syncthreads();
#pragma unroll
        for (int p = 0; p < 4; p++) {
            int r = srow + p * 16;
            float4 fw = *reinterpret_cast<const float4*>(Wb + (size_t)(mb + r) * S_ + kb + scol);
            *reinterpret_cast<uint2*>((char*)Ws + swz(r, scol * 2)) = pack4(fw);
        }
        {
            const float* vp = V + (size_t)b * S_ * D_ + (size_t)kb * D_ + t;
#pragma unroll
            for (int c = 0; c < 8; c++) {
                float f[8];
#pragma unroll
                for (int j = 0; j < 8; j++) f[j] = vp[j * D_];
                vp += 8 * D_;
                union { __bf16 h[8]; uint4 u; } r;
#pragma unroll
                for (int j = 0; j < 8; j++) r.h[j] = (__bf16)f[j];
                *reinterpret_cast<uint4*>((char*)Vs + swz(t, c * 16)) = r.u;
            }
        }
        __syncthreads();
#pragma unroll
        for (int ks = 0; ks < 2; ks++) {
            const int kby = ks * 64 + (lane >> 4) * 16;
            bf16x8 a[4], bv[4];
#pragma unroll
            for (int m = 0; m < 4; m++)
                a[m] = *reinterpret_cast<const bf16x8*>((const char*)Ws + swz(m * 16 + (lane & 15), kby));
#pragma unroll
            for (int n = 0; n < 4; n++)
                bv[n] = *reinterpret_cast<const bf16x8*>((const char*)Vs + swz(wv * 64 + n * 16 + (lane & 15), kby));
#pragma unroll
            for (int m = 0; m < 4; m++)
#pragma unroll
                for (int n = 0; n < 4; n++)
                    acc[m][n] = __builtin_amdgcn_mfma_f32_16x16x32_bf16(a[m], bv[n], acc[m][n], 0, 0, 0);
        }
    }

    float* Ob = Out + (size_t)b * S_ * D_;
#pragma unroll
    for (int m = 0; m < 4; m++) {
#pragma unroll
        for (int j = 0; j < 4; j++) {
            int row = mb + m * 16 + (lane >> 4) * 4 + j;
            float* rp = Ob + (size_t)row * D_ + wv * 64 + (lane & 15);
#pragma unroll
            for (int n = 0; n < 4; n++) rp[n * 16] = acc[m][n][j];
        }
    }
}

extern "C" void kernel_launch(void* const* d_in, const int* in_sizes, int n_in,
                              void* d_out, int out_size, void* d_ws, size_t ws_size,
                              hipStream_t stream) {
    const float* Q = (const float*)d_in[0];
    const float* K = (const float*)d_in[1];
    const float* V = (const float*)d_in[2];
    float* out = (float*)d_out;                 // B*S*D fp32
    float* Wt = out + (size_t)B_ * S_ * D_;     // B*S*S fp32 weights

    const size_t vt_bytes = (size_t)B_ * D_ * S_ * 2;        // 8 MiB
    const size_t st_bytes = (size_t)B_ * S_ * NCT * 8;       // 4 MiB
    const size_t fin_bytes = (size_t)B_ * S_ * 8;            // 128 KiB

    if (ws_size >= vt_bytes + st_bytes + fin_bytes) {
        unsigned short* Vtg = (unsigned short*)d_ws;
        float2* stats = (float2*)((char*)d_ws + vt_bytes);
        float2* finals = (float2*)((char*)d_ws + vt_bytes + st_bytes);
        k_vt<<<dim3(S_ / 64, D_ / 64, B_), 256, 0, stream>>>(V, Vtg);
        k_qk<true><<<dim3(S_ / 128, S_ / 128, B_), 256, 0, stream>>>(Q, K, Wt, stats);
        k_reduce<<<(B_ * S_) / 256, 256, 0, stream>>>(stats, finals);
        k_pvn<<<dim3(S_ / 32, B_), 256, 0, stream>>>(Wt, Vtg, finals, out);
    } else {
        k_qk<false><<<dim3(S_ / 128, S_ / 128, B_), 256, 0, stream>>>(Q, K, Wt, nullptr);
        k_softmax<<<B_ * S_, 256, 0, stream>>>(Wt);
        k_pv_fb<<<dim3(S_ / 64, B_), 256, 0, stream>>>(Wt, V, out);
    }
}

// Round 4
// 523.238 us; speedup vs baseline: 1.2819x; 1.2819x over previous
//
#include <hip/hip_runtime.h>
#include <hip/hip_bf16.h>
#include <hip/hip_fp16.h>

#define S_ 4096
#define D_ 256
#define B_ 4
#define NCT 32  // 128-wide col tiles per row in k_qk

static constexpr float INV_SCALE = 0.08838834764831844f; // 1/sqrt(128)

typedef _Float16 f16x8 __attribute__((ext_vector_type(8)));
typedef float f32x4 __attribute__((ext_vector_type(4)));

// XOR swizzle for [row][128B] LDS tiles
__device__ __forceinline__ int swz(int row, int kbyte) {
    return (row * 128 + kbyte) ^ ((row & 7) << 4);
}
// XOR swizzle for [row][256B] LDS tiles
__device__ __forceinline__ int swz256(int row, int kbyte) {
    return (row * 256 + kbyte) ^ ((row & 7) << 4);
}

// async global->LDS, 16B per lane; dst is wave-uniform base (+lane*16 by HW)
__device__ __forceinline__ void gload16(const void* g, void* l) {
    __builtin_amdgcn_global_load_lds((const __attribute__((address_space(1))) void*)g,
                                     (__attribute__((address_space(3))) void*)l, 16, 0, 0);
}

__device__ __forceinline__ uint2 pack4bf(float4 f) {
    union { __bf16 h[4]; uint2 u; } r;
    r.h[0] = (__bf16)f.x; r.h[1] = (__bf16)f.y;
    r.h[2] = (__bf16)f.z; r.h[3] = (__bf16)f.w;
    return r.u;
}

// ---------------------------------------------------------------------------
// k_cvt: fp32 -> fp16 elementwise for Q (y=0) and K (y=1)
// ---------------------------------------------------------------------------
__global__ __launch_bounds__(256) void k_cvt(const float* __restrict__ Q,
                                             const float* __restrict__ K,
                                             _Float16* __restrict__ Qh,
                                             _Float16* __restrict__ Kh) {
    const float* src = blockIdx.y ? K : Q;
    _Float16* dst = blockIdx.y ? Kh : Qh;
    size_t i = ((size_t)blockIdx.x * 256 + threadIdx.x) * 8;
    float4 f0 = *reinterpret_cast<const float4*>(src + i);
    float4 f1 = *reinterpret_cast<const float4*>(src + i + 4);
    union { _Float16 h[8]; uint4 u; } r;
    r.h[0] = (_Float16)f0.x; r.h[1] = (_Float16)f0.y;
    r.h[2] = (_Float16)f0.z; r.h[3] = (_Float16)f0.w;
    r.h[4] = (_Float16)f1.x; r.h[5] = (_Float16)f1.y;
    r.h[6] = (_Float16)f1.z; r.h[7] = (_Float16)f1.w;
    *reinterpret_cast<uint4*>(dst + i) = r.u;
}

// ---------------------------------------------------------------------------
// k_vt16: V [b][4096][256] fp32 -> Vt [b][256][4096] fp16
// ---------------------------------------------------------------------------
__global__ __launch_bounds__(256) void k_vt16(const float* __restrict__ V,
                                              _Float16* __restrict__ Vt) {
    __shared__ float tile[64][65];
    const int t = threadIdx.x;
    const int kb = blockIdx.x * 64;  // S dim
    const int nb = blockIdx.y * 64;  // D dim
    const int b = blockIdx.z;
    const float* Vb = V + (size_t)b * S_ * D_;
    {
        const int r = t >> 2, c4 = (t & 3) * 16;
#pragma unroll
        for (int j = 0; j < 4; j++) {
            float4 f = *reinterpret_cast<const float4*>(Vb + (size_t)(kb + r) * D_ + nb + c4 + j * 4);
            tile[r][c4 + j * 4 + 0] = f.x;
            tile[r][c4 + j * 4 + 1] = f.y;
            tile[r][c4 + j * 4 + 2] = f.z;
            tile[r][c4 + j * 4 + 3] = f.w;
        }
    }
    __syncthreads();
    {
        const int n = t >> 2, k4 = (t & 3) * 16;
        union { _Float16 h[16]; uint4 u[2]; } o;
#pragma unroll
        for (int j = 0; j < 16; j++) o.h[j] = (_Float16)tile[k4 + j][n];
        _Float16* Ob = Vt + (size_t)b * D_ * S_ + (size_t)(nb + n) * S_ + kb + k4;
        *reinterpret_cast<uint4*>(Ob) = o.u[0];
        *reinterpret_cast<uint4*>(Ob + 8) = o.u[1];
    }
}

// ---------------------------------------------------------------------------
// k_qk16: raw scores = Qh . Kh^T (fp16 MFMA), stats to ws, raw fp16 scores
// packed into the upper half of each 4096-float W row (bytes 8192..16383).
// tile 128x128, BK=64, 4 waves 2x2. global_load_lds staging, swizzled source.
// ---------------------------------------------------------------------------
__global__ __launch_bounds__(256) void k_qk16(const _Float16* __restrict__ Qh,
                                              const _Float16* __restrict__ Kh,
                                              float* __restrict__ Wt,
                                              float2* __restrict__ stats) {
    __shared__ alignas(16) _Float16 QK[2 * 128 * 64];  // Qs | Ks, reused as Cs[128][256B]
    __shared__ float s_mx[4][64];
    __shared__ float s_sm[4][64];
    const int t = threadIdx.x, lane = t & 63, wv = t >> 6;
    const int wm = wv >> 1, wn = wv & 1;
    const int grp = lane >> 4;
    // XCD-aware bijective swizzle of the 4096-block 1D grid
    const int gid = blockIdx.x;
    const int sz = (gid & 7) * 512 + (gid >> 3);
    const int bz = sz >> 10, by = (sz >> 5) & 31, bx = sz & 31;
    const int mb = bx * 128, nb = by * 128;
    const char* Qb = (const char*)(Qh + (size_t)bz * S_ * D_);
    const char* Kb = (const char*)(Kh + (size_t)bz * S_ * D_);

    f32x4 acc[4][4];
#pragma unroll
    for (int i = 0; i < 4; i++)
#pragma unroll
        for (int j = 0; j < 4; j++) acc[i][j] = f32x4{0.f, 0.f, 0.f, 0.f};

    for (int kb = 0; kb < D_; kb += 64) {
        __syncthreads();  // previous iter's fragment reads done
#pragma unroll
        for (int p = 0; p < 4; p++) {
            int L = p * 4096 + wv * 1024 + lane * 16;      // linear dest byte in 16KB tile
            int row = L >> 7;                               // 0..127
            int c = (L & 127) ^ ((row & 7) << 4);           // inverse-swizzled source col byte
            gload16(Qb + (size_t)(mb + row) * 512 + (size_t)kb * 2 + c,
                    (char*)QK + p * 4096 + wv * 1024);
            gload16(Kb + (size_t)(nb + row) * 512 + (size_t)kb * 2 + c,
                    (char*)QK + 16384 + p * 4096 + wv * 1024);
        }
        __syncthreads();  // staging complete (compiler drains vmcnt at barrier)
#pragma unroll
        for (int ks = 0; ks < 2; ks++) {
            const int kby = ks * 64 + grp * 16;
            f16x8 a[4], bb[4];
#pragma unroll
            for (int m = 0; m < 4; m++)
                a[m] = *reinterpret_cast<const f16x8*>((const char*)QK + swz(wm * 64 + m * 16 + (lane & 15), kby));
#pragma unroll
            for (int n = 0; n < 4; n++)
                bb[n] = *reinterpret_cast<const f16x8*>((const char*)QK + 16384 + swz(wn * 64 + n * 16 + (lane & 15), kby));
#pragma unroll
            for (int m = 0; m < 4; m++)
#pragma unroll
                for (int n = 0; n < 4; n++)
                    acc[m][n] = __builtin_amdgcn_mfma_f32_16x16x32_f16(a[m], bb[n], acc[m][n], 0, 0, 0);
        }
    }

    // per-row tile stats (exact fp32 acc)
#pragma unroll
    for (int m = 0; m < 4; m++) {
#pragma unroll
        for (int j = 0; j < 4; j++) {
            float s0 = acc[m][0][j] * INV_SCALE;
            float s1 = acc[m][1][j] * INV_SCALE;
            float s2 = acc[m][2][j] * INV_SCALE;
            float s3 = acc[m][3][j] * INV_SCALE;
            float mx = fmaxf(fmaxf(s0, s1), fmaxf(s2, s3));
#pragma unroll
            for (int o = 8; o; o >>= 1) mx = fmaxf(mx, __shfl_xor(mx, o, 64));
            float se = __expf(s0 - mx) + __expf(s1 - mx) + __expf(s2 - mx) + __expf(s3 - mx);
#pragma unroll
            for (int o = 8; o; o >>= 1) se += __shfl_xor(se, o, 64);
            if ((lane & 15) == 0) {
                int rw = m * 16 + grp * 4 + j;
                s_mx[wv][rw] = mx;
                s_sm[wv][rw] = se;
            }
        }
    }
    __syncthreads();  // also guarantees all waves done reading QK fragments
    if (t < 128) {
        int wm2 = t >> 6, rw = t & 63;
        float m0 = s_mx[wm2 * 2][rw], m1 = s_mx[wm2 * 2 + 1][rw];
        float mm = fmaxf(m0, m1);
        float ll = s_sm[wm2 * 2][rw] * __expf(m0 - mm) + s_sm[wm2 * 2 + 1][rw] * __expf(m1 - mm);
        int row = mb + wm2 * 64 + rw;
        stats[((size_t)bz * S_ + row) * NCT + by] = make_float2(mm, ll);
    }

    // acc -> Cs (fp16, swizzled 256B rows) -> coalesced global fp16 raw
#pragma unroll
    for (int m = 0; m < 4; m++)
#pragma unroll
        for (int n = 0; n < 4; n++)
#pragma unroll
            for (int j = 0; j < 4; j++) {
                int rl = wm * 64 + m * 16 + grp * 4 + j;
                int cl = wn * 64 + n * 16 + (lane & 15);
                *reinterpret_cast<_Float16*>((char*)QK + swz256(rl, cl * 2)) = (_Float16)acc[m][n][j];
            }
    __syncthreads();
    float* Wb = Wt + (size_t)bz * S_ * S_;
#pragma unroll
    for (int p = 0; p < 8; p++) {
        int r = (t >> 4) + p * 16;
        int cby = (t & 15) * 16;
        uint4 v = *reinterpret_cast<const uint4*>((const char*)QK + swz256(r, cby));
        char* gp = (char*)(Wb + (size_t)(mb + r) * S_ + 2048) + nb * 2 + cby;
        *reinterpret_cast<uint4*>(gp) = v;
    }
}

// ---------------------------------------------------------------------------
// k_reduce: combine 32 per-tile (max,sumexp) partials -> (m, 1/l) per row
// ---------------------------------------------------------------------------
__global__ __launch_bounds__(256) void k_reduce(const float2* __restrict__ stats,
                                                float2* __restrict__ finals) {
    const int r = blockIdx.x * 256 + threadIdx.x;
    const float2* p = stats + (size_t)r * NCT;
    float2 v[NCT];
    float m = -1e30f;
#pragma unroll
    for (int i = 0; i < NCT; i++) { v[i] = p[i]; m = fmaxf(m, v[i].x); }
    float l = 0.f;
#pragma unroll
    for (int i = 0; i < NCT; i++) l += v[i].y * __expf(v[i].x - m);
    finals[r] = make_float2(m, 1.0f / l);
}

// ---------------------------------------------------------------------------
// k_pvn16: read raw fp16 scores (upper half of W rows), w = exp(s*sc-m)*invl,
// write fp32 W (final output) + accumulate Out = W.V via fp16 MFMA.
// Mtile=32, BK=128, 512 thr (8 waves 2Mx4N). Vs via global_load_lds.
// ---------------------------------------------------------------------------
__global__ __launch_bounds__(512) void k_pvn16(float* __restrict__ Wt,
                                               const _Float16* __restrict__ Vtg,
                                               const float2* __restrict__ finals,
                                               float* __restrict__ Out) {
    __shared__ alignas(16) _Float16 Vs[256 * 128];  // 64 KB
    __shared__ alignas(16) _Float16 Ws[32 * 128];   // 8 KB
    const int t = threadIdx.x, lane = t & 63, wv = t >> 6;
    // XCD-aware bijective swizzle of the 512-block 1D grid
    const int gid = blockIdx.x;
    const int sz = (gid & 7) * 64 + (gid >> 3);
    const int b = sz >> 7, mb = (sz & 127) * 32;
    const int wm2 = wv >> 2, wn2 = wv & 3;
    float* Wb = Wt + (size_t)b * S_ * S_;
    const char* Vtb = (const char*)(Vtg + (size_t)b * D_ * S_);
    const int rrow = t >> 4, cb = (t & 15) * 8;
    const float2 st = finals[(size_t)b * S_ + mb + rrow];
    const float mrow = st.x, invl = st.y;
    float* wrow = Wb + (size_t)(mb + rrow) * S_;

    f32x4 acc[4];
#pragma unroll
    for (int n = 0; n < 4; n++) acc[n] = f32x4{0.f, 0.f, 0.f, 0.f};

    for (int kb = 0; kb < S_; kb += 128) {
        __syncthreads();  // previous iter's fragment reads done
        // stage V^T tile [256][128] via gload_lds, inverse-swizzled source
#pragma unroll
        for (int p = 0; p < 8; p++) {
            int L = p * 8192 + wv * 1024 + lane * 16;
            int row = L >> 8;
            int c = (L & 255) ^ ((row & 7) << 4);
            gload16(Vtb + (size_t)row * 8192 + (size_t)kb * 2 + c,
                    (char*)Vs + p * 8192 + wv * 1024);
        }
        // raw fp16 -> w -> fp32 W global + fp16 Ws LDS
        {
            uint4 rv = *reinterpret_cast<const uint4*>((const char*)(wrow + 2048) + (size_t)kb * 2 + cb * 2);
            union { uint4 u; _Float16 h[8]; } ru; ru.u = rv;
            float w[8];
#pragma unroll
            for (int i2 = 0; i2 < 8; i2++)
                w[i2] = __expf((float)ru.h[i2] * INV_SCALE - mrow) * invl;
            float4 w0 = {w[0], w[1], w[2], w[3]};
            float4 w1 = {w[4], w[5], w[6], w[7]};
            *reinterpret_cast<float4*>(wrow + kb + cb) = w0;
            *reinterpret_cast<float4*>(wrow + kb + cb + 4) = w1;
            union { _Float16 h[8]; uint4 u; } pk;
#pragma unroll
            for (int i2 = 0; i2 < 8; i2++) pk.h[i2] = (_Float16)w[i2];
            *reinterpret_cast<uint4*>((char*)Ws + swz256(rrow, cb * 2)) = pk.u;
        }
        __syncthreads();
#pragma unroll
        for (int ks = 0; ks < 4; ks++) {
            const int kby = ks * 64 + (lane >> 4) * 16;
            f16x8 a = *reinterpret_cast<const f16x8*>((const char*)Ws + swz256(wm2 * 16 + (lane & 15), kby));
            f16x8 bv[4];
#pragma unroll
            for (int n = 0; n < 4; n++)
                bv[n] = *reinterpret_cast<const f16x8*>((const char*)Vs + swz256(wn2 * 64 + n * 16 + (lane & 15), kby));
#pragma unroll
            for (int n = 0; n < 4; n++)
                acc[n] = __builtin_amdgcn_mfma_f32_16x16x32_f16(a, bv[n], acc[n], 0, 0, 0);
        }
    }

    float* Ob = Out + (size_t)b * S_ * D_;
#pragma unroll
    for (int j = 0; j < 4; j++) {
        int row = mb + wm2 * 16 + (lane >> 4) * 4 + j;
        float* rp = Ob + (size_t)row * D_ + wn2 * 64 + (lane & 15);
#pragma unroll
        for (int n = 0; n < 4; n++) rp[n * 16] = acc[n][j];
    }
}

// ---------------------------------------------------------------------------
// Fallback path (no workspace): round-2 known-good structure, bf16 internals
// ---------------------------------------------------------------------------
typedef __bf16 bf16x8 __attribute__((ext_vector_type(8)));

__global__ __launch_bounds__(256) void k_qk_fb(const float* __restrict__ Q,
                                               const float* __restrict__ Km,
                                               float* __restrict__ Wt) {
    __shared__ alignas(16) unsigned short Qs[128 * 64];
    __shared__ alignas(16) unsigned short Ks[128 * 64];
    const int t = threadIdx.x, lane = t & 63, wv = t >> 6;
    const int wm = wv >> 1, wn = wv & 1;
    const int mb = blockIdx.x * 128, nb = blockIdx.y * 128;
    const int b = blockIdx.z;
    const float* Qb = Q + (size_t)b * S_ * D_;
    const float* Kb = Km + (size_t)b * S_ * D_;
    f32x4 acc[4][4];
#pragma unroll
    for (int i = 0; i < 4; i++)
#pragma unroll
        for (int j = 0; j < 4; j++) acc[i][j] = f32x4{0.f, 0.f, 0.f, 0.f};
    const int srow = t >> 4, scol = (t & 15) * 4;
    for (int kb = 0; kb < D_; kb += 64) {
        __syncthreads();
#pragma unroll
        for (int h = 0; h < 2; h++) {
            float4 fq[4], fk[4];
#pragma unroll
            for (int p = 0; p < 4; p++) {
                int r = srow + (h * 4 + p) * 16;
                fq[p] = *reinterpret_cast<const float4*>(Qb + (size_t)(mb + r) * D_ + kb + scol);
                fk[p] = *reinterpret_cast<const float4*>(Kb + (size_t)(nb + r) * D_ + kb + scol);
            }
#pragma unroll
            for (int p = 0; p < 4; p++) {
                int r = srow + (h * 4 + p) * 16;
                *reinterpret_cast<uint2*>((char*)Qs + swz(r, scol * 2)) = pack4bf(fq[p]);
                *reinterpret_cast<uint2*>((char*)Ks + swz(r, scol * 2)) = pack4bf(fk[p]);
            }
        }
        __syncthreads();
#pragma unroll
        for (int ks = 0; ks < 2; ks++) {
            const int kby = ks * 64 + (lane >> 4) * 16;
            bf16x8 a[4], bb[4];
#pragma unroll
            for (int m = 0; m < 4; m++)
                a[m] = *reinterpret_cast<const bf16x8*>((const char*)Qs + swz(wm * 64 + m * 16 + (lane & 15), kby));
#pragma unroll
            for (int n = 0; n < 4; n++)
                bb[n] = *reinterpret_cast<const bf16x8*>((const char*)Ks + swz(wn * 64 + n * 16 + (lane & 15), kby));
#pragma unroll
            for (int m = 0; m < 4; m++)
#pragma unroll
                for (int n = 0; n < 4; n++)
                    acc[m][n] = __builtin_amdgcn_mfma_f32_16x16x32_bf16(a[m], bb[n], acc[m][n], 0, 0, 0);
        }
    }
    float* Wb = Wt + (size_t)b * S_ * S_;
#pragma unroll
    for (int m = 0; m < 4; m++)
#pragma unroll
        for (int j = 0; j < 4; j++) {
            int row = mb + wm * 64 + m * 16 + (lane >> 4) * 4 + j;
            float* rp = Wb + (size_t)row * S_ + nb + wn * 64 + (lane & 15);
#pragma unroll
            for (int n = 0; n < 4; n++) rp[n * 16] = acc[m][n][j];
        }
}

__global__ __launch_bounds__(256) void k_softmax(float* __restrict__ Wt) {
    const size_t row = blockIdx.x;
    float* p = Wt + row * S_;
    const int t = threadIdx.x, lane = t & 63, wv = t >> 6;
    __shared__ float red[4];
    float4 x[4];
#pragma unroll
    for (int j = 0; j < 4; j++)
        x[j] = *reinterpret_cast<const float4*>(p + t * 4 + j * 1024);
    float mx = -1e30f;
#pragma unroll
    for (int j = 0; j < 4; j++) {
        x[j].x *= INV_SCALE; x[j].y *= INV_SCALE;
        x[j].z *= INV_SCALE; x[j].w *= INV_SCALE;
        mx = fmaxf(mx, fmaxf(fmaxf(x[j].x, x[j].y), fmaxf(x[j].z, x[j].w)));
    }
#pragma unroll
    for (int o = 32; o; o >>= 1) mx = fmaxf(mx, __shfl_xor(mx, o, 64));
    if (lane == 0) red[wv] = mx;
    __syncthreads();
    mx = fmaxf(fmaxf(red[0], red[1]), fmaxf(red[2], red[3]));
    __syncthreads();
    float sum = 0.f;
#pragma unroll
    for (int j = 0; j < 4; j++) {
        x[j].x = __expf(x[j].x - mx); x[j].y = __expf(x[j].y - mx);
        x[j].z = __expf(x[j].z - mx); x[j].w = __expf(x[j].w - mx);
        sum += x[j].x + x[j].y + x[j].z + x[j].w;
    }
#pragma unroll
    for (int o = 32; o; o >>= 1) sum += __shfl_xor(sum, o, 64);
    if (lane == 0) red[wv] = sum;
    __syncthreads();
    sum = red[0] + red[1] + red[2] + red[3];
    const float r = 1.0f / sum;
#pragma unroll
    for (int j = 0; j < 4; j++) {
        x[j].x *= r; x[j].y *= r; x[j].z *= r; x[j].w *= r;
        *reinterpret_cast<float4*>(p + t * 4 + j * 1024) = x[j];
    }
}

__global__ __launch_bounds__(256) void k_pv_fb(const float* __restrict__ Wt,
                                               const float* __restrict__ V,
                                               float* __restrict__ Out) {
    __shared__ alignas(16) unsigned short Ws[64 * 64];
    __shared__ alignas(16) unsigned short Vsh[256 * 64];
    const int t = threadIdx.x, lane = t & 63, wv = t >> 6;
    const int mb = blockIdx.x * 64;
    const int b = blockIdx.y;
    const float* Wb = Wt + (size_t)b * S_ * S_;
    f32x4 acc[4][4];
#pragma unroll
    for (int i = 0; i < 4; i++)
#pragma unroll
        for (int j = 0; j < 4; j++) acc[i][j] = f32x4{0.f, 0.f, 0.f, 0.f};
    const int srow = t >> 4, scol = (t & 15) * 4;
    for (int kb = 0; kb < S_; kb += 64) {
        __syncthreads();
#pragma unroll
        for (int p = 0; p < 4; p++) {
            int r = srow + p * 16;
            float4 fw = *reinterpret_cast<const float4*>(Wb + (size_t)(mb + r) * S_ + kb + scol);
            *reinterpret_cast<uint2*>((char*)Ws + swz(r, scol * 2)) = pack4bf(fw);
        }
        {
            const float* vp = V + (size_t)b * S_ * D_ + (size_t)kb * D_ + t;
#pragma unroll
            for (int c = 0; c < 8; c++) {
                float f[8];
#pragma unroll
                for (int j = 0; j < 8; j++) f[j] = vp[j * D_];
                vp += 8 * D_;
                union { __bf16 h[8]; uint4 u; } r;
#pragma unroll
                for (int j = 0; j < 8; j++) r.h[j] = (__bf16)f[j];
                *reinterpret_cast<uint4*>((char*)Vsh + swz(t, c * 16)) = r.u;
            }
        }
        __syncthreads();
#pragma unroll
        for (int ks = 0; ks < 2; ks++) {
            const int kby = ks * 64 + (lane >> 4) * 16;
            bf16x8 a[4], bv[4];
#pragma unroll
            for (int m = 0; m < 4; m++)
                a[m] = *reinterpret_cast<const bf16x8*>((const char*)Ws + swz(m * 16 + (lane & 15), kby));
#pragma unroll
            for (int n = 0; n < 4; n++)
                bv[n] = *reinterpret_cast<const bf16x8*>((const char*)Vsh + swz(wv * 64 + n * 16 + (lane & 15), kby));
#pragma unroll
            for (int m = 0; m < 4; m++)
#pragma unroll
                for (int n = 0; n < 4; n++)
                    acc[m][n] = __builtin_amdgcn_mfma_f32_16x16x32_bf16(a[m], bv[n], acc[m][n], 0, 0, 0);
        }
    }
    float* Ob = Out + (size_t)b * S_ * D_;
#pragma unroll
    for (int m = 0; m < 4; m++)
#pragma unroll
        for (int j = 0; j < 4; j++) {
            int row = mb + m * 16 + (lane >> 4) * 4 + j;
            float* rp = Ob + (size_t)row * D_ + wv * 64 + (lane & 15);
#pragma unroll
            for (int n = 0; n < 4; n++) rp[n * 16] = acc[m][n][j];
        }
}

extern "C" void kernel_launch(void* const* d_in, const int* in_sizes, int n_in,
                              void* d_out, int out_size, void* d_ws, size_t ws_size,
                              hipStream_t stream) {
    const float* Q = (const float*)d_in[0];
    const float* K = (const float*)d_in[1];
    const float* V = (const float*)d_in[2];
    float* out = (float*)d_out;                 // B*S*D fp32
    float* Wt = out + (size_t)B_ * S_ * D_;     // B*S*S fp32 weights

    const size_t qh_off = 0;                          // 8 MiB
    const size_t kh_off = qh_off + (size_t)B_ * S_ * D_ * 2;
    const size_t vt_off = kh_off + (size_t)B_ * S_ * D_ * 2;
    const size_t st_off = vt_off + (size_t)B_ * D_ * S_ * 2;
    const size_t fin_off = st_off + (size_t)B_ * S_ * NCT * 8;
    const size_t total = fin_off + (size_t)B_ * S_ * 8;

    if (ws_size >= total) {
        _Float16* Qh = (_Float16*)((char*)d_ws + qh_off);
        _Float16* Kh = (_Float16*)((char*)d_ws + kh_off);
        _Float16* Vtg = (_Float16*)((char*)d_ws + vt_off);
        float2* stats = (float2*)((char*)d_ws + st_off);
        float2* finals = (float2*)((char*)d_ws + fin_off);
        k_cvt<<<dim3((B_ * S_ * D_) / (256 * 8), 2), 256, 0, stream>>>(Q, K, Qh, Kh);
        k_vt16<<<dim3(S_ / 64, D_ / 64, B_), 256, 0, stream>>>(V, Vtg);
        k_qk16<<<(S_ / 128) * (S_ / 128) * B_, 256, 0, stream>>>(Qh, Kh, Wt, stats);
        k_reduce<<<(B_ * S_) / 256, 256, 0, stream>>>(stats, finals);
        k_pvn16<<<(S_ / 32) * B_, 512, 0, stream>>>(Wt, Vtg, finals, out);
    } else {
        k_qk_fb<<<dim3(S_ / 128, S_ / 128, B_), 256, 0, stream>>>(Q, K, Wt);
        k_softmax<<<B_ * S_, 256, 0, stream>>>(Wt);
        k_pv_fb<<<dim3(S_ / 64, B_), 256, 0, stream>>>(Wt, V, out);
    }
}